// Round 8
// baseline (118.754 us; speedup 1.0000x reference)
//
#include <hip/hip_runtime.h>

// binary_decoder: bit-exact float32 emulation of the reference's sequential
// carry-save adder.
//
// Round-11. Model (fits r4-r10): period/step = max(#instr*4.6cy issue,
// links * ~13cy lone-wave dependent latency). r9/r10 = 4 links = 52cy.
// This round cuts the cycle to 3 links by running the chain HALVED (exact
// x0.5 scaling; rounding commutes with exact power-of-2 scaling):
//   T = t/2 in [0,2):  s'/2 = fract(T)  (one op replaces and+sub)
//                      carry = floor(T) in {0,1}  (parallel with fract)
//   Uh' = fma(a, 0.5, fr)  -- folds the addend's halving into the rounding
//                             op: a*0.5 exact => round(a*0.5+fr) ==
//                             round((s'+a)/2) == uu'/2.  x stays unhalved.
//
// Per-step blob (7 instr):
//   1 v_fmac_f32   Uh, cmd, kq    ; T = Uh + cmd*kq   (kq = 0.5 masked)
//   2 v_fract_f32  fr, Uh         ; s'/2        [sum cycle]
//   3 v_floor_f32  fl, Uh         ; carry {0,1} [carry cycle, parallel]
//   4 v_fma_f32    Uh, a, 0.5, fr ; Uh' = a/2 + fr  (a ORIGINAL domain)
//   5 v_bfe_i32    m, bits, J, 1  ; a-prep f+2 (off-chain)
//   6 v_mov_b32_dpp cmd, fl       ; carry shift (fl@3 -> gap 4,5 = 2 ok)
//   7 v_and_b32    a, xs, m       ; a = bit ? x : +0  (x >= 0, SGPR x)
// Sum cycle: 1->2->4->1' = 3 links. Carry cycle: 1->3->6->1' = 3 links.
// Issue 7*4.6=33cy < 3*13=39cy -> latency-bound at ~39cy/step (~34us).
//
// Exactness: T < 2 strict (t < 4); fract/floor exact there (Sterbenz);
// cmd*kq in {0,0.5} exact so fmac == round(Uh + c/2) single-rounding ==
// t/2 by scale-commute; fma a*0.5 exact; destination-side mask kq=0 at
// lane&7==0 == reference's MSB-carry drop (verified form since r9).
// Final: s_out = 2*fr (exact); c_out = cmd*kq1, kq1 in {0,1}.

#define F_DIM 2048
#define K_DIM 4096
#define B_DIM 8
#define NG    (F_DIM / 32)   // 64 packed dwords per chain-column
#define NSB   (F_DIM / 64)   // 32 superblocks of 64 steps

#define PK_BYTES (64 * NG * 64 * 4)  // 1 MB: [og][f32][lane] dwords

typedef int v16i __attribute__((ext_vector_type(16)));

__device__ __forceinline__ float dpp_row_shr1(float v) {
    int r = __builtin_amdgcn_update_dpp(0, __float_as_int(v), 0x111, 0xf, 0xf, true);
    return __int_as_float(r);
}

__device__ __forceinline__ int sext_bit(unsigned bits, int u) {
#if __has_builtin(__builtin_amdgcn_sbfe)
    return __builtin_amdgcn_sbfe((int)bits, (unsigned)u, 1u);
#else
    return ((int)(bits << (31 - u))) >> 31;
#endif
}

// ---------------- pass 1: pack (w >= 0.5) bits -----------------------------
__global__ __launch_bounds__(64) void pack_kernel(const float* __restrict__ w,
                                                  unsigned* __restrict__ pk) {
    const int lane = threadIdx.x;
    const int og   = blockIdx.x;
    const int f32  = blockIdx.y;
    const float* wp = w + og * 64 + lane;
    unsigned bits = 0;
#pragma unroll
    for (int j = 0; j < 32; ++j) {
        float wv = wp[(f32 * 32 + j) * K_DIM];
        bits |= (wv >= 0.5f ? 1u : 0u) << j;
    }
    pk[(og * 64 + f32) * 64 + lane] = bits;
}

// ---------------- pass 2: the sequential chain (halved domain) -------------

#define B(PKv, JLIT, XVAL) {                                                  \
    const int xs_ = (XVAL);                                                   \
    asm("v_fmac_f32 %[uh], %[cm], %[kq]\n\t"                                  \
        "v_fract_f32 %[fr], %[uh]\n\t"                                        \
        "v_floor_f32 %[fl], %[uh]\n\t"                                        \
        "v_fma_f32 %[uh], %[a], 0.5, %[fr]\n\t"                               \
        "v_bfe_i32 %[m], %[bits], " #JLIT ", 1\n\t"                           \
        "v_mov_b32_dpp %[cm], %[fl] row_shr:1 row_mask:0xf bank_mask:0xf bound_ctrl:0\n\t" \
        "v_and_b32 %[a], %[xs], %[m]"                                         \
        : [fr]"=&v"(fr_), [fl]"=&v"(fl_), [m]"=&v"(m_),                       \
          [uh]"+v"(Uh), [a]"+v"(a), [cm]"+v"(cmd)                             \
        : [bits]"v"(PKv), [xs]"s"(xs_), [kq]"v"(kq));                         \
}

// 64 steps of superblock S. Blob j (step S*64+j) preps a for step S*64+j+2:
// bit e=j+2 of the window {PN[1:0], P1, P0}; x element e from four dwordx16
// chunks of this superblock + the next superblock's first chunk.
#define SB64(P0, P1, PN, CQ, CQN) {                                           \
    v16i q0 = xv[(CQ)+0], q1 = xv[(CQ)+1], q2 = xv[(CQ)+2], q3 = xv[(CQ)+3];  \
    v16i qn = xv[(CQN)];                                                      \
    B(P0, 2,q0[ 2]) B(P0, 3,q0[ 3]) B(P0, 4,q0[ 4]) B(P0, 5,q0[ 5])          \
    B(P0, 6,q0[ 6]) B(P0, 7,q0[ 7]) B(P0, 8,q0[ 8]) B(P0, 9,q0[ 9])          \
    B(P0,10,q0[10]) B(P0,11,q0[11]) B(P0,12,q0[12]) B(P0,13,q0[13])          \
    B(P0,14,q0[14]) B(P0,15,q0[15])                                           \
    B(P0,16,q1[ 0]) B(P0,17,q1[ 1]) B(P0,18,q1[ 2]) B(P0,19,q1[ 3])          \
    B(P0,20,q1[ 4]) B(P0,21,q1[ 5]) B(P0,22,q1[ 6]) B(P0,23,q1[ 7])          \
    B(P0,24,q1[ 8]) B(P0,25,q1[ 9]) B(P0,26,q1[10]) B(P0,27,q1[11])          \
    B(P0,28,q1[12]) B(P0,29,q1[13]) B(P0,30,q1[14]) B(P0,31,q1[15])          \
    B(P1, 0,q2[ 0]) B(P1, 1,q2[ 1]) B(P1, 2,q2[ 2]) B(P1, 3,q2[ 3])          \
    B(P1, 4,q2[ 4]) B(P1, 5,q2[ 5]) B(P1, 6,q2[ 6]) B(P1, 7,q2[ 7])          \
    B(P1, 8,q2[ 8]) B(P1, 9,q2[ 9]) B(P1,10,q2[10]) B(P1,11,q2[11])          \
    B(P1,12,q2[12]) B(P1,13,q2[13]) B(P1,14,q2[14]) B(P1,15,q2[15])          \
    B(P1,16,q3[ 0]) B(P1,17,q3[ 1]) B(P1,18,q3[ 2]) B(P1,19,q3[ 3])          \
    B(P1,20,q3[ 4]) B(P1,21,q3[ 5]) B(P1,22,q3[ 6]) B(P1,23,q3[ 7])          \
    B(P1,24,q3[ 8]) B(P1,25,q3[ 9]) B(P1,26,q3[10]) B(P1,27,q3[11])          \
    B(P1,28,q3[12]) B(P1,29,q3[13]) B(P1,30,q3[14]) B(P1,31,q3[15])          \
    B(PN, 0,qn[ 0]) B(PN, 1,qn[ 1])                                           \
}

__global__ __launch_bounds__(64, 1) void csa_main(const float* __restrict__ x,
                                                  const unsigned* __restrict__ pk,
                                                  float* __restrict__ out) {
    const int lane = threadIdx.x;
    const int og   = blockIdx.x + 8 * blockIdx.y;  // 0..63
    const int b    = blockIdx.z;                   // 0..7
    const int k    = og * 64 + lane;

    // Destination-side halved-carry mask: 0 at each group's LSB lane, else 0.5.
    const float kqf = ((lane & 7) == 0) ? 0.0f : 0.5f;
    float kq = kqf;

    const unsigned* bp = pk + og * (NG * 64) + lane;      // dword g at bp[g*64]
    const v16i*     xv = (const v16i*)(x + b * F_DIM);    // uniform -> scalar path
    const int*      xi = (const int*)(x + b * F_DIM);

    // pk double-buffer: slot A = superblock sb, slot B = sb+1.
    unsigned pA0 = bp[0 * 64], pA1 = bp[1 * 64];
    unsigned pB0 = bp[2 * 64], pB1 = bp[3 * 64];

    // Prologue (plain C): Uh = uu_0/2 = a_0*0.5 (exact); a holds a_1
    // (original domain); cmd = 0 so blob 0's fmac adds +0 (== ref c_0 = 0).
    int   xs0 = xi[0], xs1 = xi[1];
    float a0  = __int_as_float(sext_bit(pA0, 0) & xs0);
    float a   = __int_as_float(sext_bit(pA0, 1) & xs1);
    float Uh  = a0 * 0.5f;
    float cmd = 0.0f;
    float fr_ = 0.0f, fl_ = 0.0f;
    int   m_;

#pragma clang loop unroll(disable)
    for (int sb = 0; sb < NSB; sb += 2) {   // 16 iterations, 128 steps each
        SB64(pA0, pA1, pB0, sb * 4, sb * 4 + 4);
        {   // refill slot A -> superblock sb+2 (clamped tail re-read)
            int nsb = sb + 2; int csb = (nsb < NSB) ? nsb : (NSB - 2);
            pA0 = bp[(2 * csb + 0) * 64];
            pA1 = bp[(2 * csb + 1) * 64];
        }
        int cqn = (sb * 4 + 8 < 128) ? (sb * 4 + 8) : 127;  // dummy x at tail
        SB64(pB0, pB1, pA0, sb * 4 + 4, cqn);
        {   // refill slot B -> superblock sb+3
            int nsb = sb + 3; int csb = (nsb < NSB) ? nsb : (NSB - 2);
            pB0 = bp[(2 * csb + 0) * 64];
            pB1 = bp[(2 * csb + 1) * 64];
        }
    }

    // s_final = 2*fr_2047 (exact; the tail-garbage a_2048 only corrupted Uh,
    // which is dead). c_final = dpp(fl_2047)*mask in {0,1}: cmd already holds
    // the shifted carry from the last blob's mov_dpp.
    const float kq1 = ((lane & 7) == 0) ? 0.0f : 1.0f;
    float s_out = fr_ * 2.0f;
    float cfin  = cmd * kq1;
    out[b * K_DIM + k]                 = s_out;
    out[B_DIM * K_DIM + b * K_DIM + k] = cfin;
}

#undef SB64
#undef B

// ---------------- fallback (direct-w kernel) if ws is too small ------------
#define U_FB  16
#define NB_FB 4
__global__ __launch_bounds__(64, 1) void csa_fallback(const float* __restrict__ x,
                                                      const float* __restrict__ weight,
                                                      float* __restrict__ out) {
    const int lane = threadIdx.x;
    const int og   = blockIdx.x + 8 * blockIdx.y;
    const int b    = blockIdx.z;
    const int k    = og * 64 + lane;
    const float kmask = ((lane & 7) == 7) ? 0.0f : 1.0f;
    int zero;
    asm volatile("v_mov_b32 %0, 0" : "=v"(zero));
    const float*  wp  = weight + k;
    const float4* xp4 = (const float4*)(x + b * F_DIM) + zero;
    float  wb[NB_FB][U_FB];
    float4 xb[NB_FB][U_FB / 4];
#pragma unroll
    for (int p = 0; p < NB_FB; ++p) {
#pragma unroll
        for (int u = 0; u < U_FB; ++u) wb[p][u] = wp[(p * U_FB + u) * K_DIM];
#pragma unroll
        for (int q = 0; q < U_FB / 4; ++q) xb[p][q] = xp4[(p * U_FB) / 4 + q];
    }
    float s = 0.0f, c = 0.0f;
    for (int f0 = 0; f0 < F_DIM; f0 += NB_FB * U_FB) {
#pragma unroll
        for (int p = 0; p < NB_FB; ++p) {
            const float* xf = (const float*)&xb[p][0];
#pragma unroll
            for (int u = 0; u < U_FB; ++u) {
                float av = (wb[p][u] >= 0.5f) ? xf[u] : 0.0f;
                float uu = s + av;
                float t  = uu + c;
                bool  ge = (t >= 2.0f);
                float hh = ge ? kmask : 0.0f;
                s = ge ? (t - 2.0f) : t;
                c = dpp_row_shr1(hh);
            }
            int fb = f0 + p * U_FB + NB_FB * U_FB;
            int fc = (fb <= F_DIM - U_FB) ? fb : (F_DIM - U_FB);
#pragma unroll
            for (int u = 0; u < U_FB; ++u) wb[p][u] = wp[(fc + u) * K_DIM];
#pragma unroll
            for (int q = 0; q < U_FB / 4; ++q) xb[p][q] = xp4[fc / 4 + q];
        }
    }
    out[b * K_DIM + k]                 = s;
    out[B_DIM * K_DIM + b * K_DIM + k] = c;
}

extern "C" void kernel_launch(void* const* d_in, const int* in_sizes, int n_in,
                              void* d_out, int out_size, void* d_ws, size_t ws_size,
                              hipStream_t stream) {
    (void)in_sizes; (void)n_in; (void)out_size;
    const float* x      = (const float*)d_in[0];
    const float* weight = (const float*)d_in[1];
    float* out          = (float*)d_out;

    if (ws_size >= (size_t)PK_BYTES && d_ws != nullptr) {
        unsigned* pk = (unsigned*)d_ws;
        pack_kernel<<<dim3(64, 64, 1), dim3(64), 0, stream>>>(weight, pk);
        csa_main<<<dim3(8, 8, 8), dim3(64), 0, stream>>>(x, pk, out);
    } else {
        csa_fallback<<<dim3(8, 8, 8), dim3(64), 0, stream>>>(x, weight, out);
    }
}

// Round 9
// 114.670 us; speedup vs baseline: 1.0356x; 1.0356x over previous
//
#include <hip/hip_runtime.h>

// binary_decoder: bit-exact float32 emulation of the reference's sequential
// carry-save adder.
//
// Round-12. Model update (r5-r11 data): asm-blob variants are ISSUE-limited
// at ~7.5-8 cy/instr for a lone wave (period tracks #instr: r9 6i=48.5,
// r10 7i=52.7, r11 7i/3links=52.9 -- links don't matter). So: minimize
// instructions. This round fuses r11's halved domain (fract/floor replace
// and+sub; verified absmax 0.0) with r9's dpp-fused fmac (verified absmax
// 0.0): 6 instr AND 3 links.
//
// Per-step blob (6 instr):
//   1 v_fmac_f32_dpp Uh, fl, kq row_shr:1 ; T = Uh + dpp(floor)*0.5mask
//   2 v_fract_f32  fr, Uh                 ; s'/2   [sum cycle]
//   3 v_floor_f32  fl, Uh                 ; carry {0,1} [carry cycle]
//   4 v_fma_f32    Uh, a, 0.5, fr        ; Uh' = a/2 + fr (a un-halved)
//   5 v_bfe_i32    m, bits, J, 1         ; a-prep f+2 (off-chain)
//   6 v_and_b32    a, xs, m              ; a = bit ? x : +0 (x>=0, SGPR x)
// Sum cycle 1->2->4->1' = 3 links; carry cycle 1->3->1'' = 3 links.
// DPP producer hazard: fl written slot 3, consumed by NEXT blob's slot-1
// DPP -> gap = slots 4,5,6 = 3 instr >= 2 ok; first blob guarded by
// s_nop 1 in the fl-init asm.
//
// Exactness (both halves field-proven): halved domain r11 (T<2 strict;
// fract/floor exact; dpp(fl)*kq in {0,0.5} exact -> fmac single-rounds
// == round(Uh + c/2) == t/2 by exact power-of-2 scale-commute; fma a*0.5
// exact); dpp-fused fmac r9. Destination-side mask kq=0 at lane&7==0 ==
// reference's MSB-carry drop. Final: s = 2*fr exact; c = dpp(fl)*{0,1}.

#define F_DIM 2048
#define K_DIM 4096
#define B_DIM 8
#define NG    (F_DIM / 32)   // 64 packed dwords per chain-column
#define NSB   (F_DIM / 64)   // 32 superblocks of 64 steps

#define PK_BYTES (64 * NG * 64 * 4)  // 1 MB: [og][f32][lane] dwords

typedef int v16i __attribute__((ext_vector_type(16)));

__device__ __forceinline__ float dpp_row_shr1(float v) {
    int r = __builtin_amdgcn_update_dpp(0, __float_as_int(v), 0x111, 0xf, 0xf, true);
    return __int_as_float(r);
}

__device__ __forceinline__ int sext_bit(unsigned bits, int u) {
#if __has_builtin(__builtin_amdgcn_sbfe)
    return __builtin_amdgcn_sbfe((int)bits, (unsigned)u, 1u);
#else
    return ((int)(bits << (31 - u))) >> 31;
#endif
}

// ---------------- pass 1: pack (w >= 0.5) bits -----------------------------
__global__ __launch_bounds__(64) void pack_kernel(const float* __restrict__ w,
                                                  unsigned* __restrict__ pk) {
    const int lane = threadIdx.x;
    const int og   = blockIdx.x;
    const int f32  = blockIdx.y;
    const float* wp = w + og * 64 + lane;
    unsigned bits = 0;
#pragma unroll
    for (int j = 0; j < 32; ++j) {
        float wv = wp[(f32 * 32 + j) * K_DIM];
        bits |= (wv >= 0.5f ? 1u : 0u) << j;
    }
    pk[(og * 64 + f32) * 64 + lane] = bits;
}

// ---------------- pass 2: the sequential chain (halved, dpp-fused) ---------

#define B(PKv, JLIT, XVAL) {                                                  \
    const int xs_ = (XVAL);                                                   \
    asm("v_fmac_f32_dpp %[uh], %[fl], %[kq] row_shr:1 row_mask:0xf bank_mask:0xf bound_ctrl:0\n\t" \
        "v_fract_f32 %[fr], %[uh]\n\t"                                        \
        "v_floor_f32 %[fl], %[uh]\n\t"                                        \
        "v_fma_f32 %[uh], %[a], 0.5, %[fr]\n\t"                               \
        "v_bfe_i32 %[m], %[bits], " #JLIT ", 1\n\t"                           \
        "v_and_b32 %[a], %[xs], %[m]"                                         \
        : [fr]"=&v"(fr_), [m]"=&v"(m_),                                       \
          [uh]"+v"(Uh), [a]"+v"(a), [fl]"+v"(fl_)                             \
        : [bits]"v"(PKv), [xs]"s"(xs_), [kq]"v"(kq));                         \
}

// 64 steps of superblock S. Blob j (step S*64+j) preps a for step S*64+j+2:
// bit e=j+2 of the window {PN[1:0], P1, P0}; x element e from four dwordx16
// chunks of this superblock + the next superblock's first chunk.
#define SB64(P0, P1, PN, CQ, CQN) {                                           \
    v16i q0 = xv[(CQ)+0], q1 = xv[(CQ)+1], q2 = xv[(CQ)+2], q3 = xv[(CQ)+3];  \
    v16i qn = xv[(CQN)];                                                      \
    B(P0, 2,q0[ 2]) B(P0, 3,q0[ 3]) B(P0, 4,q0[ 4]) B(P0, 5,q0[ 5])          \
    B(P0, 6,q0[ 6]) B(P0, 7,q0[ 7]) B(P0, 8,q0[ 8]) B(P0, 9,q0[ 9])          \
    B(P0,10,q0[10]) B(P0,11,q0[11]) B(P0,12,q0[12]) B(P0,13,q0[13])          \
    B(P0,14,q0[14]) B(P0,15,q0[15])                                           \
    B(P0,16,q1[ 0]) B(P0,17,q1[ 1]) B(P0,18,q1[ 2]) B(P0,19,q1[ 3])          \
    B(P0,20,q1[ 4]) B(P0,21,q1[ 5]) B(P0,22,q1[ 6]) B(P0,23,q1[ 7])          \
    B(P0,24,q1[ 8]) B(P0,25,q1[ 9]) B(P0,26,q1[10]) B(P0,27,q1[11])          \
    B(P0,28,q1[12]) B(P0,29,q1[13]) B(P0,30,q1[14]) B(P0,31,q1[15])          \
    B(P1, 0,q2[ 0]) B(P1, 1,q2[ 1]) B(P1, 2,q2[ 2]) B(P1, 3,q2[ 3])          \
    B(P1, 4,q2[ 4]) B(P1, 5,q2[ 5]) B(P1, 6,q2[ 6]) B(P1, 7,q2[ 7])          \
    B(P1, 8,q2[ 8]) B(P1, 9,q2[ 9]) B(P1,10,q2[10]) B(P1,11,q2[11])          \
    B(P1,12,q2[12]) B(P1,13,q2[13]) B(P1,14,q2[14]) B(P1,15,q2[15])          \
    B(P1,16,q3[ 0]) B(P1,17,q3[ 1]) B(P1,18,q3[ 2]) B(P1,19,q3[ 3])          \
    B(P1,20,q3[ 4]) B(P1,21,q3[ 5]) B(P1,22,q3[ 6]) B(P1,23,q3[ 7])          \
    B(P1,24,q3[ 8]) B(P1,25,q3[ 9]) B(P1,26,q3[10]) B(P1,27,q3[11])          \
    B(P1,28,q3[12]) B(P1,29,q3[13]) B(P1,30,q3[14]) B(P1,31,q3[15])          \
    B(PN, 0,qn[ 0]) B(PN, 1,qn[ 1])                                           \
}

__global__ __launch_bounds__(64, 1) void csa_main(const float* __restrict__ x,
                                                  const unsigned* __restrict__ pk,
                                                  float* __restrict__ out) {
    const int lane = threadIdx.x;
    const int og   = blockIdx.x + 8 * blockIdx.y;  // 0..63
    const int b    = blockIdx.z;                   // 0..7
    const int k    = og * 64 + lane;

    // Destination-side halved-carry mask: 0 at each group's LSB lane, else 0.5.
    const float kqf = ((lane & 7) == 0) ? 0.0f : 0.5f;
    float kq = kqf;

    const unsigned* bp = pk + og * (NG * 64) + lane;      // dword g at bp[g*64]
    const v16i*     xv = (const v16i*)(x + b * F_DIM);    // uniform -> scalar path
    const int*      xi = (const int*)(x + b * F_DIM);

    // pk double-buffer: slot A = superblock sb, slot B = sb+1.
    unsigned pA0 = bp[0 * 64], pA1 = bp[1 * 64];
    unsigned pB0 = bp[2 * 64], pB1 = bp[3 * 64];

    // Prologue: Uh = uu_0/2 = a_0*0.5 (exact); a holds a_1 (original
    // domain); fl = 0 so blob 0's fmac_dpp adds +0 (== ref c_0 = 0).
    // s_nop 1 guarantees the DPP-producer gap for the first blob.
    int   xs0 = xi[0], xs1 = xi[1];
    float a0  = __int_as_float(sext_bit(pA0, 0) & xs0);
    float a   = __int_as_float(sext_bit(pA0, 1) & xs1);
    float Uh  = a0 * 0.5f;
    float fr_ = 0.0f, fl_;
    int   m_;
    asm("v_mov_b32 %0, 0\n\ts_nop 1" : "=&v"(fl_));   // no inputs -> no alias risk

#pragma clang loop unroll(disable)
    for (int sb = 0; sb < NSB; sb += 2) {   // 16 iterations, 128 steps each
        SB64(pA0, pA1, pB0, sb * 4, sb * 4 + 4);
        {   // refill slot A -> superblock sb+2 (clamped tail re-read)
            int nsb = sb + 2; int csb = (nsb < NSB) ? nsb : (NSB - 2);
            pA0 = bp[(2 * csb + 0) * 64];
            pA1 = bp[(2 * csb + 1) * 64];
        }
        int cqn = (sb * 4 + 8 < 128) ? (sb * 4 + 8) : 127;  // dummy x at tail
        SB64(pB0, pB1, pA0, sb * 4 + 4, cqn);
        {   // refill slot B -> superblock sb+3
            int nsb = sb + 3; int csb = (nsb < NSB) ? nsb : (NSB - 2);
            pB0 = bp[(2 * csb + 0) * 64];
            pB1 = bp[(2 * csb + 1) * 64];
        }
    }

    // s_final = 2*fr_2047 (exact; tail-garbage only corrupted dead Uh).
    // c_final = dpp(fl_2047) masked to {0,1} (builtin handles its hazard).
    const float kq1 = ((lane & 7) == 0) ? 0.0f : 1.0f;
    float s_out = fr_ * 2.0f;
    float cfin  = dpp_row_shr1(fl_) * kq1;
    out[b * K_DIM + k]                 = s_out;
    out[B_DIM * K_DIM + b * K_DIM + k] = cfin;
}

#undef SB64
#undef B

// ---------------- fallback (direct-w kernel) if ws is too small ------------
#define U_FB  16
#define NB_FB 4
__global__ __launch_bounds__(64, 1) void csa_fallback(const float* __restrict__ x,
                                                      const float* __restrict__ weight,
                                                      float* __restrict__ out) {
    const int lane = threadIdx.x;
    const int og   = blockIdx.x + 8 * blockIdx.y;
    const int b    = blockIdx.z;
    const int k    = og * 64 + lane;
    const float kmask = ((lane & 7) == 7) ? 0.0f : 1.0f;
    int zero;
    asm volatile("v_mov_b32 %0, 0" : "=v"(zero));
    const float*  wp  = weight + k;
    const float4* xp4 = (const float4*)(x + b * F_DIM) + zero;
    float  wb[NB_FB][U_FB];
    float4 xb[NB_FB][U_FB / 4];
#pragma unroll
    for (int p = 0; p < NB_FB; ++p) {
#pragma unroll
        for (int u = 0; u < U_FB; ++u) wb[p][u] = wp[(p * U_FB + u) * K_DIM];
#pragma unroll
        for (int q = 0; q < U_FB / 4; ++q) xb[p][q] = xp4[(p * U_FB) / 4 + q];
    }
    float s = 0.0f, c = 0.0f;
    for (int f0 = 0; f0 < F_DIM; f0 += NB_FB * U_FB) {
#pragma unroll
        for (int p = 0; p < NB_FB; ++p) {
            const float* xf = (const float*)&xb[p][0];
#pragma unroll
            for (int u = 0; u < U_FB; ++u) {
                float av = (wb[p][u] >= 0.5f) ? xf[u] : 0.0f;
                float uu = s + av;
                float t  = uu + c;
                bool  ge = (t >= 2.0f);
                float hh = ge ? kmask : 0.0f;
                s = ge ? (t - 2.0f) : t;
                c = dpp_row_shr1(hh);
            }
            int fb = f0 + p * U_FB + NB_FB * U_FB;
            int fc = (fb <= F_DIM - U_FB) ? fb : (F_DIM - U_FB);
#pragma unroll
            for (int u = 0; u < U_FB; ++u) wb[p][u] = wp[(fc + u) * K_DIM];
#pragma unroll
            for (int q = 0; q < U_FB / 4; ++q) xb[p][q] = xp4[fc / 4 + q];
        }
    }
    out[b * K_DIM + k]                 = s;
    out[B_DIM * K_DIM + b * K_DIM + k] = c;
}

extern "C" void kernel_launch(void* const* d_in, const int* in_sizes, int n_in,
                              void* d_out, int out_size, void* d_ws, size_t ws_size,
                              hipStream_t stream) {
    (void)in_sizes; (void)n_in; (void)out_size;
    const float* x      = (const float*)d_in[0];
    const float* weight = (const float*)d_in[1];
    float* out          = (float*)d_out;

    if (ws_size >= (size_t)PK_BYTES && d_ws != nullptr) {
        unsigned* pk = (unsigned*)d_ws;
        pack_kernel<<<dim3(64, 64, 1), dim3(64), 0, stream>>>(weight, pk);
        csa_main<<<dim3(8, 8, 8), dim3(64), 0, stream>>>(x, pk, out);
    } else {
        csa_fallback<<<dim3(8, 8, 8), dim3(64), 0, stream>>>(x, weight, out);
    }
}